// Round 15
// baseline (57.274 us; speedup 1.0000x reference)
//
#include <hip/hip_runtime.h>
#include <stdint.h>

#define N_       8
#define IC_      16
#define C1_      2048
#define H_       56
#define W_       56
#define THREADS_ 1024
#define ROWU_    8          // dwords per LDS row (16px bf16)
#define TPB_     7          // stages per block (1792 tiles / 256 blocks)

typedef float    vf4 __attribute__((ext_vector_type(4)));
typedef uint32_t vu2 __attribute__((ext_vector_type(2)));

__device__ __forceinline__ uint32_t cvt_pk_bf16(float lo, float hi) {
    uint32_t r;
    asm("v_cvt_pk_bf16_f32 %0, %1, %2" : "=v"(r) : "v"(lo), "v"(hi));
    return r;   // [15:0]=bf16(lo) [31:16]=bf16(hi), RNE
}

// LDS-only barrier: waits DS ops, leaves global stores in flight.
__device__ __forceinline__ void barrier_lds() {
    asm volatile("s_waitcnt lgkmcnt(0)\n\ts_barrier" ::: "memory");
}

#define LO_(u) __uint_as_float((u) << 16)
#define HI_(u) __uint_as_float((u) & 0xffff0000u)

// XOR pair-swizzle (r8): phase-1 write conflicts 16->4-way, reads <=4-way.
__device__ __forceinline__ int swz_pair(int row, int pair) {
    return (pair ^ (((row >> 2) & 3) << 1));
}

// Conv of one tile (all 2048 channels) into buf.
// LPAD: tile touches w=-1 (zero). RPAD: tile touches w=56 (zero).
template <int TW, bool LPAD, bool RPAD>
__device__ __forceinline__ void conv_tile(uint32_t* __restrict__ buf,
                                          const int n, const int h, const int w0,
                                          const int tid,
                                          const float* __restrict__ x,
                                          const float (&w)[2][9], const float (&bias)[2])
{
    #pragma unroll
    for (int p = 0; p < 2; ++p) {
        const int c  = p * THREADS_ + tid;
        const int ci = __builtin_amdgcn_readfirstlane(c >> 7);   // wave-uniform
        const float* xb = x + (size_t)((n * IC_ + ci) * H_) * W_;

        float win[3][TW + 2];                  // wave-uniform -> scalar regs
        #pragma unroll
        for (int rr = 0; rr < 3; ++rr) {
            const int r = h - 1 + rr;
            if ((unsigned)r < (unsigned)H_) {  // uniform branch
                const float* rp = xb + r * W_;
                win[rr][0] = LPAD ? 0.0f : rp[w0 - 1];
                #pragma unroll
                for (int v = 0; v < TW / 4; ++v) {              // 16B-aligned f4 loads
                    const vf4 t = *(const vf4*)(rp + w0 + 4 * v);
                    win[rr][1+4*v]=t.x; win[rr][2+4*v]=t.y;
                    win[rr][3+4*v]=t.z; win[rr][4+4*v]=t.w;
                }
                win[rr][TW + 1] = RPAD ? 0.0f : rp[w0 + TW];
            } else {
                #pragma unroll
                for (int k = 0; k < TW + 2; ++k) win[rr][k] = 0.0f;
            }
        }

        float acc[TW];
        #pragma unroll
        for (int q = 0; q < TW; ++q) acc[q] = bias[p];
        #pragma unroll
        for (int dr = 0; dr < 3; ++dr)
            #pragma unroll
            for (int dc = 0; dc < 3; ++dc) {
                const float wk = w[p][dr * 3 + dc];
                #pragma unroll
                for (int q = 0; q < TW; ++q)
                    acc[q] = fmaf(win[dr][q + dc], wk, acc[q]);
            }

        uint32_t* row = &buf[c * ROWU_];
        #pragma unroll
        for (int m = 0; m < TW / 4; ++m) {
            vu2 pr;
            pr.x = cvt_pk_bf16(acc[4*m + 0], acc[4*m + 1]);
            pr.y = cvt_pk_bf16(acc[4*m + 2], acc[4*m + 3]);
            *(vu2*)(row + swz_pair(c, 2 * m)) = pr;   // ds_write_b64
        }
    }
}

// Pixel-major gather (16px tiles): every 4-lane group = one aligned 64B line
// that is never re-read -> NONTEMPORAL store (skip L2 write-allocate churn).
__device__ __forceinline__ void gather16(const uint32_t* __restrict__ buf,
                                         const int n, const int h, const int w0,
                                         const int q, const int jb,
                                         const int (&rows)[8][4],
                                         float* __restrict__ out)
{
    #pragma unroll 4
    for (int it = 0; it < 8; ++it) {
        const int j  = it * 256 + jb;
        const int r0 = rows[it][0], r1 = rows[it][1];
        const int r2 = rows[it][2], r3 = rows[it][3];
        const vu2 a  = *(const vu2*)(&buf[r0 * ROWU_ + swz_pair(r0, 2*q)]);
        const vu2 b  = *(const vu2*)(&buf[r1 * ROWU_ + swz_pair(r1, 2*q)]);
        const vu2 cv = *(const vu2*)(&buf[r2 * ROWU_ + swz_pair(r2, 2*q)]);
        const vu2 d  = *(const vu2*)(&buf[r3 * ROWU_ + swz_pair(r3, 2*q)]);
        vf4 o;
        o.x = fmaxf(fmaxf(LO_(a.x), LO_(b.x)), fmaxf(LO_(cv.x), LO_(d.x)));
        o.y = fmaxf(fmaxf(HI_(a.x), HI_(b.x)), fmaxf(HI_(cv.x), HI_(d.x)));
        o.z = fmaxf(fmaxf(LO_(a.y), LO_(b.y)), fmaxf(LO_(cv.y), LO_(d.y)));
        o.w = fmaxf(fmaxf(HI_(a.y), HI_(b.y)), fmaxf(HI_(cv.y), HI_(d.y)));
        float* op = out + (size_t)(n * C1_ + j) * (H_ * W_) + h * W_ + w0 + 4 * q;
        __builtin_nontemporal_store(o, (vf4*)op);   // full line, streaming
    }
}

// 8px tile (32B half-line): REGULAR store so L2 merges it with the
// parity-sibling row's half (written same stage, same XCD cohort).
__device__ __forceinline__ void gather8(const uint32_t* __restrict__ buf,
                                        const int n, const int h, const int w0,
                                        const int tid,
                                        const int* __restrict__ idx,
                                        float* __restrict__ out)
{
    const int q  = tid & 1;
    const int jb = tid >> 1;
    #pragma unroll 4
    for (int it = 0; it < 4; ++it) {
        const int j = it * 512 + jb;
        const int4 iv = *(const int4*)(idx + 4 * j);
        const int r0 = iv.x & (C1_-1), r1 = iv.y & (C1_-1);
        const int r2 = iv.z & (C1_-1), r3 = iv.w & (C1_-1);
        const vu2 a  = *(const vu2*)(&buf[r0 * ROWU_ + swz_pair(r0, 2*q)]);
        const vu2 b  = *(const vu2*)(&buf[r1 * ROWU_ + swz_pair(r1, 2*q)]);
        const vu2 cv = *(const vu2*)(&buf[r2 * ROWU_ + swz_pair(r2, 2*q)]);
        const vu2 d  = *(const vu2*)(&buf[r3 * ROWU_ + swz_pair(r3, 2*q)]);
        vf4 o;
        o.x = fmaxf(fmaxf(LO_(a.x), LO_(b.x)), fmaxf(LO_(cv.x), LO_(d.x)));
        o.y = fmaxf(fmaxf(HI_(a.x), HI_(b.x)), fmaxf(HI_(cv.x), HI_(d.x)));
        o.z = fmaxf(fmaxf(LO_(a.y), LO_(b.y)), fmaxf(LO_(cv.y), LO_(d.y)));
        o.w = fmaxf(fmaxf(HI_(a.y), HI_(b.y)), fmaxf(HI_(cv.y), HI_(d.y)));
        float* op = out + (size_t)(n * C1_ + j) * (H_ * W_) + h * W_ + w0 + 4 * q;
        *(vf4*)op = o;
    }
}

// Parity-phased tile dispatch (block-uniform branches):
// even h: [0,16)L [16,32) [32,48) [48,56)R ; odd h: [0,8)L [8,24) [24,40) [40,56)R
__device__ __forceinline__ void do_conv(uint32_t* buf, int n, int h, int sel, int tid,
                                        const float* x,
                                        const float (&w)[2][9], const float (&bias)[2])
{
    if (h & 1) {
        if (sel == 3)      conv_tile<8,  true,  false>(buf, n, h, 0,           tid, x, w, bias);
        else if (sel == 2) conv_tile<16, false, true >(buf, n, h, 40,          tid, x, w, bias);
        else               conv_tile<16, false, false>(buf, n, h, 8 + sel*16,  tid, x, w, bias);
    } else {
        if (sel == 3)      conv_tile<8,  false, true >(buf, n, h, 48,          tid, x, w, bias);
        else if (sel == 0) conv_tile<16, true,  false>(buf, n, h, 0,           tid, x, w, bias);
        else               conv_tile<16, false, false>(buf, n, h, sel*16,      tid, x, w, bias);
    }
}

__device__ __forceinline__ void do_gather(const uint32_t* buf, int n, int h, int sel,
                                          int tid, int q, int jb, const int (&rows)[8][4],
                                          const int* idx, float* out)
{
    if (h & 1) {
        if (sel == 3) gather8 (buf, n, h, 0,          tid, idx, out);
        else          gather16(buf, n, h, 8 + sel*16, q, jb, rows, out);
    } else {
        if (sel == 3) gather8 (buf, n, h, 48,         tid, idx, out);
        else          gather16(buf, n, h, sel*16,     q, jb, rows, out);
    }
}

// Tile schedule (r11): XCD-cohort. n = xcd; at stage k the 32 blocks of an XCD
// cover rows h = k*8..k*8+7 completely -> sibling lines written together.
__device__ __forceinline__ void tile_coords(int xcd, int lb, int k,
                                            int& n, int& h, int& sel) {
    const int tl = k * 32 + lb;               // 0..223
    n = xcd; h = tl >> 2; sel = tl & 3;
}

// r13 pipeline: dbuf + LDS-only barriers + wave-parity stagger.
__global__ __launch_bounds__(THREADS_, 4)
void rptn_pipe(const float* __restrict__ x, const float* __restrict__ W1,
               const float* __restrict__ b1, const int* __restrict__ idx,
               float* __restrict__ out)
{
    __shared__ uint32_t s[2][C1_ * ROWU_];     // 2 x 64 KB = 128 KB
    const int tid = threadIdx.x;
    const int xcd = blockIdx.x & 7;
    const int lb  = blockIdx.x >> 3;           // 0..31 within XCD cohort
    const bool convFirst = (tid >> 6) & 1;     // wave-parity stagger

    // weights + bias hoisted once per block
    float w[2][9], bias[2];
    #pragma unroll
    for (int p = 0; p < 2; ++p) {
        const float* wp = W1 + (size_t)(p * THREADS_ + tid) * 9;
        #pragma unroll
        for (int k = 0; k < 9; ++k) w[p][k] = wp[k];
        bias[p] = b1[p * THREADS_ + tid];
    }

    // gather row-indices hoisted once per block (16px mapping)
    const int q  = tid & 3;
    const int jb = tid >> 2;
    int rows[8][4];
    #pragma unroll
    for (int it = 0; it < 8; ++it) {
        const int4 iv = *(const int4*)(idx + 4 * (it * 256 + jb));
        rows[it][0] = iv.x & (C1_-1); rows[it][1] = iv.y & (C1_-1);
        rows[it][2] = iv.z & (C1_-1); rows[it][3] = iv.w & (C1_-1);
    }

    int pn, ph, psel;                           // previous tile (pending gather)
    {
        tile_coords(xcd, lb, 0, pn, ph, psel);
        do_conv(s[0], pn, ph, psel, tid, x, w, bias);
    }
    barrier_lds();

    #pragma unroll 1
    for (int k = 1; k < TPB_; ++k) {
        int nn, hh, sel;
        tile_coords(xcd, lb, k, nn, hh, sel);

        if (convFirst) {
            do_conv  (s[k&1],     nn, hh, sel,  tid, x, w, bias);
            do_gather(s[(k-1)&1], pn, ph, psel, tid, q, jb, rows, idx, out);
        } else {
            do_gather(s[(k-1)&1], pn, ph, psel, tid, q, jb, rows, idx, out);
            do_conv  (s[k&1],     nn, hh, sel,  tid, x, w, bias);
        }

        barrier_lds();
        pn = nn; ph = hh; psel = sel;
    }
    do_gather(s[(TPB_-1)&1], pn, ph, psel, tid, q, jb, rows, idx, out);
}

extern "C" void kernel_launch(void* const* d_in, const int* in_sizes, int n_in,
                              void* d_out, int out_size, void* d_ws, size_t ws_size,
                              hipStream_t stream)
{
    const float* x   = (const float*)d_in[0];
    const float* W1  = (const float*)d_in[1];
    const float* b1  = (const float*)d_in[2];
    const int* idxp  = (const int*)d_in[3];
    float* out       = (float*)d_out;

    dim3 grid(256);              // 8 XCD cohorts x 32 blocks; 7 stages each
    dim3 block(THREADS_);
    hipLaunchKernelGGL(rptn_pipe, grid, block, 0, stream, x, W1, b1, idxp, out);
}

// Round 16
// 54.777 us; speedup vs baseline: 1.0456x; 1.0456x over previous
//
#include <hip/hip_runtime.h>
#include <stdint.h>

#define N_       8
#define IC_      16
#define C1_      2048
#define H_       56
#define W_       56
#define THREADS_ 1024
#define ROWU_    8          // dwords per LDS row (16px bf16)
#define TPB_     7          // stages per block (1792 tiles / 256 blocks)

typedef float    vf4 __attribute__((ext_vector_type(4)));
typedef uint32_t vu2 __attribute__((ext_vector_type(2)));

__device__ __forceinline__ uint32_t cvt_pk_bf16(float lo, float hi) {
    uint32_t r;
    asm("v_cvt_pk_bf16_f32 %0, %1, %2" : "=v"(r) : "v"(lo), "v"(hi));
    return r;   // [15:0]=bf16(lo) [31:16]=bf16(hi), RNE
}

// LDS-only barrier: waits DS ops, leaves global stores in flight.
__device__ __forceinline__ void barrier_lds() {
    asm volatile("s_waitcnt lgkmcnt(0)\n\ts_barrier" ::: "memory");
}

#define LO_(u) __uint_as_float((u) << 16)
#define HI_(u) __uint_as_float((u) & 0xffff0000u)

// XOR pair-swizzle (r8): phase-1 write conflicts 16->4-way, reads <=4-way.
__device__ __forceinline__ int swz_pair(int row, int pair) {
    return (pair ^ (((row >> 2) & 3) << 1));
}

// Conv of one tile (all 2048 channels) into buf.
// LPAD: tile touches w=-1 (zero). RPAD: tile touches w=56 (zero).
template <int TW, bool LPAD, bool RPAD>
__device__ __forceinline__ void conv_tile(uint32_t* __restrict__ buf,
                                          const int n, const int h, const int w0,
                                          const int tid,
                                          const float* __restrict__ x,
                                          const float (&w)[2][9], const float (&bias)[2])
{
    #pragma unroll
    for (int p = 0; p < 2; ++p) {
        const int c  = p * THREADS_ + tid;
        const int ci = __builtin_amdgcn_readfirstlane(c >> 7);   // wave-uniform
        const float* xb = x + (size_t)((n * IC_ + ci) * H_) * W_;

        float win[3][TW + 2];                  // wave-uniform -> scalar regs
        #pragma unroll
        for (int rr = 0; rr < 3; ++rr) {
            const int r = h - 1 + rr;
            if ((unsigned)r < (unsigned)H_) {  // uniform branch
                const float* rp = xb + r * W_;
                win[rr][0] = LPAD ? 0.0f : rp[w0 - 1];
                #pragma unroll
                for (int v = 0; v < TW / 4; ++v) {              // 16B-aligned f4 loads
                    const vf4 t = *(const vf4*)(rp + w0 + 4 * v);
                    win[rr][1+4*v]=t.x; win[rr][2+4*v]=t.y;
                    win[rr][3+4*v]=t.z; win[rr][4+4*v]=t.w;
                }
                win[rr][TW + 1] = RPAD ? 0.0f : rp[w0 + TW];
            } else {
                #pragma unroll
                for (int k = 0; k < TW + 2; ++k) win[rr][k] = 0.0f;
            }
        }

        float acc[TW];
        #pragma unroll
        for (int q = 0; q < TW; ++q) acc[q] = bias[p];
        #pragma unroll
        for (int dr = 0; dr < 3; ++dr)
            #pragma unroll
            for (int dc = 0; dc < 3; ++dc) {
                const float wk = w[p][dr * 3 + dc];
                #pragma unroll
                for (int q = 0; q < TW; ++q)
                    acc[q] = fmaf(win[dr][q + dc], wk, acc[q]);
            }

        uint32_t* row = &buf[c * ROWU_];
        #pragma unroll
        for (int m = 0; m < TW / 4; ++m) {
            vu2 pr;
            pr.x = cvt_pk_bf16(acc[4*m + 0], acc[4*m + 1]);
            pr.y = cvt_pk_bf16(acc[4*m + 2], acc[4*m + 3]);
            *(vu2*)(row + swz_pair(c, 2 * m)) = pr;   // ds_write_b64
        }
    }
}

// Pixel-major gather (16px tiles), preloaded row indices, full-line stores.
// With parity-phased w0, every 4-lane group is one aligned 64B line.
__device__ __forceinline__ void gather16(const uint32_t* __restrict__ buf,
                                         const int n, const int h, const int w0,
                                         const int q, const int jb,
                                         const int (&rows)[8][4],
                                         float* __restrict__ out)
{
    #pragma unroll 4
    for (int it = 0; it < 8; ++it) {
        const int j  = it * 256 + jb;
        const int r0 = rows[it][0], r1 = rows[it][1];
        const int r2 = rows[it][2], r3 = rows[it][3];
        const vu2 a  = *(const vu2*)(&buf[r0 * ROWU_ + swz_pair(r0, 2*q)]);
        const vu2 b  = *(const vu2*)(&buf[r1 * ROWU_ + swz_pair(r1, 2*q)]);
        const vu2 cv = *(const vu2*)(&buf[r2 * ROWU_ + swz_pair(r2, 2*q)]);
        const vu2 d  = *(const vu2*)(&buf[r3 * ROWU_ + swz_pair(r3, 2*q)]);
        vf4 o;
        o.x = fmaxf(fmaxf(LO_(a.x), LO_(b.x)), fmaxf(LO_(cv.x), LO_(d.x)));
        o.y = fmaxf(fmaxf(HI_(a.x), HI_(b.x)), fmaxf(HI_(cv.x), HI_(d.x)));
        o.z = fmaxf(fmaxf(LO_(a.y), LO_(b.y)), fmaxf(LO_(cv.y), LO_(d.y)));
        o.w = fmaxf(fmaxf(HI_(a.y), HI_(b.y)), fmaxf(HI_(cv.y), HI_(d.y)));
        float* op = out + (size_t)(n * C1_ + j) * (H_ * W_) + h * W_ + w0 + 4 * q;
        *(vf4*)op = o;                          // one aligned 64B line per 4 lanes
    }
}

// 8px tile (32B half-line; merges in L2 with the parity-sibling row's piece).
__device__ __forceinline__ void gather8(const uint32_t* __restrict__ buf,
                                        const int n, const int h, const int w0,
                                        const int tid,
                                        const int* __restrict__ idx,
                                        float* __restrict__ out)
{
    const int q  = tid & 1;
    const int jb = tid >> 1;
    #pragma unroll 4
    for (int it = 0; it < 4; ++it) {
        const int j = it * 512 + jb;
        const int4 iv = *(const int4*)(idx + 4 * j);
        const int r0 = iv.x & (C1_-1), r1 = iv.y & (C1_-1);
        const int r2 = iv.z & (C1_-1), r3 = iv.w & (C1_-1);
        const vu2 a  = *(const vu2*)(&buf[r0 * ROWU_ + swz_pair(r0, 2*q)]);
        const vu2 b  = *(const vu2*)(&buf[r1 * ROWU_ + swz_pair(r1, 2*q)]);
        const vu2 cv = *(const vu2*)(&buf[r2 * ROWU_ + swz_pair(r2, 2*q)]);
        const vu2 d  = *(const vu2*)(&buf[r3 * ROWU_ + swz_pair(r3, 2*q)]);
        vf4 o;
        o.x = fmaxf(fmaxf(LO_(a.x), LO_(b.x)), fmaxf(LO_(cv.x), LO_(d.x)));
        o.y = fmaxf(fmaxf(HI_(a.x), HI_(b.x)), fmaxf(HI_(cv.x), HI_(d.x)));
        o.z = fmaxf(fmaxf(LO_(a.y), LO_(b.y)), fmaxf(LO_(cv.y), LO_(d.y)));
        o.w = fmaxf(fmaxf(HI_(a.y), HI_(b.y)), fmaxf(HI_(cv.y), HI_(d.y)));
        float* op = out + (size_t)(n * C1_ + j) * (H_ * W_) + h * W_ + w0 + 4 * q;
        *(vf4*)op = o;
    }
}

// Parity-phased tile dispatch (block-uniform branches):
// even h: [0,16)L [16,32) [32,48) [48,56)R ; odd h: [0,8)L [8,24) [24,40) [40,56)R
__device__ __forceinline__ void do_conv(uint32_t* buf, int n, int h, int sel, int tid,
                                        const float* x,
                                        const float (&w)[2][9], const float (&bias)[2])
{
    if (h & 1) {
        if (sel == 3)      conv_tile<8,  true,  false>(buf, n, h, 0,           tid, x, w, bias);
        else if (sel == 2) conv_tile<16, false, true >(buf, n, h, 40,          tid, x, w, bias);
        else               conv_tile<16, false, false>(buf, n, h, 8 + sel*16,  tid, x, w, bias);
    } else {
        if (sel == 3)      conv_tile<8,  false, true >(buf, n, h, 48,          tid, x, w, bias);
        else if (sel == 0) conv_tile<16, true,  false>(buf, n, h, 0,           tid, x, w, bias);
        else               conv_tile<16, false, false>(buf, n, h, sel*16,      tid, x, w, bias);
    }
}

__device__ __forceinline__ void do_gather(const uint32_t* buf, int n, int h, int sel,
                                          int tid, int q, int jb, const int (&rows)[8][4],
                                          const int* idx, float* out)
{
    if (h & 1) {
        if (sel == 3) gather8 (buf, n, h, 0,          tid, idx, out);
        else          gather16(buf, n, h, 8 + sel*16, q, jb, rows, out);
    } else {
        if (sel == 3) gather8 (buf, n, h, 48,         tid, idx, out);
        else          gather16(buf, n, h, sel*16,     q, jb, rows, out);
    }
}

// Tile schedule (r11): XCD-cohort. n = xcd; at stage k the 32 blocks of an XCD
// cover rows h = k*8..k*8+7 completely -> sibling lines written together.
__device__ __forceinline__ void tile_coords(int xcd, int lb, int k,
                                            int& n, int& h, int& sel) {
    const int tl = k * 32 + lb;               // 0..223
    n = xcd; h = tl >> 2; sel = tl & 3;
}

// r13 pipeline: dbuf + LDS-only barriers + wave-parity stagger.
__global__ __launch_bounds__(THREADS_, 4)
void rptn_pipe(const float* __restrict__ x, const float* __restrict__ W1,
               const float* __restrict__ b1, const int* __restrict__ idx,
               float* __restrict__ out)
{
    __shared__ uint32_t s[2][C1_ * ROWU_];     // 2 x 64 KB = 128 KB
    const int tid = threadIdx.x;
    const int xcd = blockIdx.x & 7;
    const int lb  = blockIdx.x >> 3;           // 0..31 within XCD cohort
    const bool convFirst = (tid >> 6) & 1;     // wave-parity stagger

    // weights + bias hoisted once per block
    float w[2][9], bias[2];
    #pragma unroll
    for (int p = 0; p < 2; ++p) {
        const float* wp = W1 + (size_t)(p * THREADS_ + tid) * 9;
        #pragma unroll
        for (int k = 0; k < 9; ++k) w[p][k] = wp[k];
        bias[p] = b1[p * THREADS_ + tid];
    }

    // gather row-indices hoisted once per block (16px mapping)
    const int q  = tid & 3;
    const int jb = tid >> 2;
    int rows[8][4];
    #pragma unroll
    for (int it = 0; it < 8; ++it) {
        const int4 iv = *(const int4*)(idx + 4 * (it * 256 + jb));
        rows[it][0] = iv.x & (C1_-1); rows[it][1] = iv.y & (C1_-1);
        rows[it][2] = iv.z & (C1_-1); rows[it][3] = iv.w & (C1_-1);
    }

    int pn, ph, psel;                           // previous tile (pending gather)
    {
        tile_coords(xcd, lb, 0, pn, ph, psel);
        do_conv(s[0], pn, ph, psel, tid, x, w, bias);
    }
    barrier_lds();

    #pragma unroll 1
    for (int k = 1; k < TPB_; ++k) {
        int nn, hh, sel;
        tile_coords(xcd, lb, k, nn, hh, sel);

        if (convFirst) {
            do_conv  (s[k&1],     nn, hh, sel,  tid, x, w, bias);
            do_gather(s[(k-1)&1], pn, ph, psel, tid, q, jb, rows, idx, out);
        } else {
            do_gather(s[(k-1)&1], pn, ph, psel, tid, q, jb, rows, idx, out);
            do_conv  (s[k&1],     nn, hh, sel,  tid, x, w, bias);
        }

        barrier_lds();
        pn = nn; ph = hh; psel = sel;
    }
    do_gather(s[(TPB_-1)&1], pn, ph, psel, tid, q, jb, rows, idx, out);
}

extern "C" void kernel_launch(void* const* d_in, const int* in_sizes, int n_in,
                              void* d_out, int out_size, void* d_ws, size_t ws_size,
                              hipStream_t stream)
{
    const float* x   = (const float*)d_in[0];
    const float* W1  = (const float*)d_in[1];
    const float* b1  = (const float*)d_in[2];
    const int* idxp  = (const int*)d_in[3];
    float* out       = (float*)d_out;

    dim3 grid(256);              // 8 XCD cohorts x 32 blocks; 7 stages each
    dim3 block(THREADS_);
    hipLaunchKernelGGL(rptn_pipe, grid, block, 0, stream, x, W1, b1, idxp, out);
}